// Round 2
// 1575.775 us; speedup vs baseline: 1.1465x; 1.1465x over previous
//
#include <hip/hip_runtime.h>
#include <hip/hip_bf16.h>
#include <math.h>

#define B_ 8
#define S_ 1024
#define HID_ 2048
#define H_ 16
#define D_ 128

typedef __attribute__((ext_vector_type(8))) short bf16x8;
typedef __attribute__((ext_vector_type(4))) float f32x4;

__device__ inline unsigned short f2b_raw(float f){
  union { __hip_bfloat16 h; unsigned short u; } cv; cv.h = __float2bfloat16(f); return cv.u;
}

__device__ inline void async_copy16(const void* g, void* l){
  __builtin_amdgcn_global_load_lds((const __attribute__((address_space(1))) unsigned int*)g,
                                   (__attribute__((address_space(3))) unsigned int*)l, 16, 0, 0);
}

// ---------------- merged f32 -> bf16 conversion (all 6 weights, contiguous dst) ----------------
__global__ __launch_bounds__(256) void cvt_all(const float* __restrict__ qw, const float* __restrict__ kw,
                                               const float* __restrict__ vw, const float* __restrict__ ow,
                                               const float* __restrict__ w1, const float* __restrict__ w2,
                                               unsigned short* __restrict__ dst){
  int i = blockIdx.x*256 + threadIdx.x;     // [0, 12582912) float4 units
  if (i >= 12582912) return;
  const float* src;
  int local;
  if      (i <  1048576){ src = qw; local = i; }
  else if (i <  2097152){ src = kw; local = i - 1048576; }
  else if (i <  3145728){ src = vw; local = i - 2097152; }
  else if (i <  4194304){ src = ow; local = i - 3145728; }
  else if (i <  8388608){ src = w1; local = i - 4194304; }
  else                  { src = w2; local = i - 8388608; }
  float4 f = ((const float4*)src)[local];
  ushort4 o;
  o.x = f2b_raw(f.x); o.y = f2b_raw(f.y); o.z = f2b_raw(f.z); o.w = f2b_raw(f.w);
  ((ushort4*)dst)[i] = o;
}

// ---------------- LayerNorm (f32 in, bf16 out), one block per row ----------------
__global__ __launch_bounds__(256) void ln_kernel(const float* __restrict__ x,
                                                 const float* __restrict__ w,
                                                 unsigned short* __restrict__ y){
  const int row = blockIdx.x, tid = threadIdx.x;
  const float* xr = x + (size_t)row*HID_;
  float4 a = ((const float4*)xr)[tid];
  float4 b = ((const float4*)xr)[tid+256];
  float s  = a.x+a.y+a.z+a.w + b.x+b.y+b.z+b.w;
  float ss = a.x*a.x+a.y*a.y+a.z*a.z+a.w*a.w + b.x*b.x+b.y*b.y+b.z*b.z+b.w*b.w;
  #pragma unroll
  for (int off=1; off<64; off<<=1){ s += __shfl_xor(s, off, 64); ss += __shfl_xor(ss, off, 64); }
  __shared__ float red[8];
  int wv = tid>>6;
  if ((tid&63)==0){ red[wv]=s; red[4+wv]=ss; }
  __syncthreads();
  s  = red[0]+red[1]+red[2]+red[3];
  ss = red[4]+red[5]+red[6]+red[7];
  float mean = s * (1.0f/HID_);
  float var  = ss * (1.0f/HID_) - mean*mean;
  float rstd = rsqrtf(var + 1e-5f);
  float4 w0 = ((const float4*)w)[tid];
  float4 w1v = ((const float4*)w)[tid+256];
  ushort4 o0, o1;
  o0.x = f2b_raw((a.x-mean)*rstd*w0.x); o0.y = f2b_raw((a.y-mean)*rstd*w0.y);
  o0.z = f2b_raw((a.z-mean)*rstd*w0.z); o0.w = f2b_raw((a.w-mean)*rstd*w0.w);
  o1.x = f2b_raw((b.x-mean)*rstd*w1v.x); o1.y = f2b_raw((b.y-mean)*rstd*w1v.y);
  o1.z = f2b_raw((b.z-mean)*rstd*w1v.z); o1.w = f2b_raw((b.w-mean)*rstd*w1v.w);
  *(ushort4*)(y + (size_t)row*HID_ + tid*4) = o0;
  *(ushort4*)(y + (size_t)row*HID_ + 1024 + tid*4) = o1;
}

// ---------------- bf16 GEMM: C[M,N] = A[M,K] @ W[N,K]^T ----------------
// 256x256 tile, BK=64, 8 waves (2Mx4N), 4-phase-per-K-tile schedule (T3+T4):
// per phase {ds_read quadrant regs | stage 1 chunk (2x global_load_lds) | vmcnt(4)+s_barrier |
//            setprio(1) 16xMFMA setprio(0) | s_barrier}. Counted vmcnt never drains to 0
// in the main loop. Chunk order per tile: A_lo, B_even, B_odd, A_hi. Queue ledger (steady
// state, entering iter t): Q={B_odd(t),A_hi(t)}; each phase issues 2 and vmcnt(4) retires
// exactly the chunk the NEXT phase's ds_read consumes (barrier in between).
// TAIL FIX (round 1): last iter (pf=false) issues nothing, so vmcnt(4) would be a no-op
// and B_odd/A_hi of the final tile would be consumed un-landed (and could land over the
// EPI-0 smem transpose buffer after the loop). Use vmcnt(0) at every boundary there.
// XOR-swizzled staging (ku = u ^ (row&7)) keeps all ds_read_b128 2-way (free).
// T1: bijective XCD swizzle (all grids divisible by 8).
// EPI 0: fused QKV epilogue (region = n0>>11): Q *scale -> (B,H,S,D);
//        K xPos-rot * zeta^seq -> (B,H,S,D); V xPos-rot / zeta^seq -> V^T (B,H,D,S)
//        via LDS 256x256 transpose for coalesced stores.
// EPI 1: f32 out = acc + res  (row-major M x N)
// EPI 2: bf16 out = gelu_exact(acc)
template<int EPI, int TAG>
__global__ __launch_bounds__(512, 2) void gemm_bt(
    const unsigned short* __restrict__ A, const unsigned short* __restrict__ W,
    unsigned short* __restrict__ out_b, float* __restrict__ out_f,
    const float* __restrict__ res,
    unsigned short* __restrict__ k_out, unsigned short* __restrict__ vt_out,
    const int* __restrict__ idxp,
    int M, int N, int K, float scale)
{
  (void)M;
  __shared__ __align__(16) unsigned short smem[65536];   // 128 KiB: A0|B0|A1|B1 (16384 shorts each)
  const int tid = threadIdx.x;
  const int lane = tid & 63, wv = tid >> 6;
  const int wm = wv >> 2, wn = wv & 3;
  const int lm = lane & 15, lg = lane >> 4;

  // XCD-aware bijective swizzle (nwg % 8 == 0 for all our grids)
  const int gx = gridDim.x;
  const int nwg = gx * gridDim.y;
  const int orig = blockIdx.y * gx + blockIdx.x;
  const int wg = (orig & 7) * (nwg >> 3) + (orig >> 3);
  const int bx = wg % gx, by = wg / gx;
  const int m0 = by << 8, n0 = bx << 8;

  f32x4 acc[8][4];
  #pragma unroll
  for (int r=0;r<8;r++)
    #pragma unroll
    for (int c=0;c<4;c++) acc[r][c] = (f32x4){0.f,0.f,0.f,0.f};

  // ds_read base offsets (shorts): frag offset added as compile-time immediate
  int oA[2], oB[2];
  #pragma unroll
  for (int kc=0;kc<2;kc++){
    const int swz = ((kc*4+lg) ^ (lm&7)) * 8;
    oA[kc] = wm*8192 + lm*64 + swz;
    oB[kc] = wn*4096 + lm*64 + swz;
  }

  // staging precompute: chunk -> (global src offset, wave-uniform LDS base)
  // A chunks (ch=0 lo rows {0-63,128-191}, ch=1 hi rows {64-127,192-255})
  // B chunks (ch=0 even rows {0-31,64-95,128-159,192-223}, ch=1 odd +32)
  int sOffA[2][2], sLdsA[2][2], sOffB[2][2], sLdsB[2][2];
  #pragma unroll
  for (int j=0;j<2;j++){
    const int unit = j*512 + tid;
    const int r7 = unit >> 3, u = unit & 7;
    const int r7g = (unit & ~63) >> 3;
    #pragma unroll
    for (int ch=0; ch<2; ch++){
      const int rowA  = (r7  & 63) + ((r7  & 64) << 1) + ch*64;
      const int rowA0 = (r7g & 63) + ((r7g & 64) << 1) + ch*64;
      sOffA[ch][j] = rowA*K + (u ^ (rowA & 7))*8;
      sLdsA[ch][j] = __builtin_amdgcn_readfirstlane(rowA0*64);
      const int rowB  = (r7  & 31) + ((r7  & 96) << 1) + ch*32;
      const int rowB0 = (r7g & 31) + ((r7g & 96) << 1) + ch*32;
      sOffB[ch][j] = rowB*K + (u ^ (rowB & 7))*8;
      sLdsB[ch][j] = __builtin_amdgcn_readfirstlane(rowB0*64);
    }
  }

  const unsigned short* Ab = A + (size_t)m0 * K;
  const unsigned short* Wb = W + (size_t)n0 * K;

  // prologue: stage tile 0 fully into buf0, drain once
  #pragma unroll
  for (int j=0;j<2;j++){
    async_copy16(Ab + sOffA[0][j], smem + sLdsA[0][j]);
    async_copy16(Ab + sOffA[1][j], smem + sLdsA[1][j]);
    async_copy16(Wb + sOffB[0][j], smem + 16384 + sLdsB[0][j]);
    async_copy16(Wb + sOffB[1][j], smem + 16384 + sLdsB[1][j]);
  }
  asm volatile("s_waitcnt vmcnt(0)\n\ts_barrier" ::: "memory");

  const int T = K >> 6;
  bf16x8 a[4][2], b[4][2];

  for (int t=0; t<T; ++t){
    const int cs = (t & 1) << 15;
    const unsigned short* sAc = smem + cs;
    const unsigned short* sBc = sAc + 16384;
    unsigned short* dA = smem + (cs ^ 32768);
    unsigned short* dB = dA + 16384;
    const int kk = (t + 1) << 6;
    const bool pf = (t + 1 < T);

    // ---- phase 1: quad (mh0,nh0); ds: A[0..3]x2 + B[0..1]x2; stage A_lo(t+1)
    #pragma unroll
    for (int r=0;r<4;r++)
      #pragma unroll
      for (int kc=0;kc<2;kc++)
        a[r][kc] = *(const bf16x8*)(sAc + oA[kc] + r*1024);
    #pragma unroll
    for (int c=0;c<2;c++)
      #pragma unroll
      for (int kc=0;kc<2;kc++)
        b[c][kc] = *(const bf16x8*)(sBc + oB[kc] + c*1024);
    if (pf){ async_copy16(Ab + sOffA[0][0] + kk, dA + sLdsA[0][0]);
             async_copy16(Ab + sOffA[0][1] + kk, dA + sLdsA[0][1]);
             asm volatile("s_waitcnt vmcnt(4)\n\ts_barrier" ::: "memory"); }
    else   { asm volatile("s_waitcnt vmcnt(0)\n\ts_barrier" ::: "memory"); }
    __builtin_amdgcn_sched_barrier(0);
    __builtin_amdgcn_s_setprio(1);
    #pragma unroll
    for (int r=0;r<4;r++)
      #pragma unroll
      for (int c=0;c<2;c++)
        #pragma unroll
        for (int kc=0;kc<2;kc++)
          acc[r][c] = __builtin_amdgcn_mfma_f32_16x16x32_bf16(a[r][kc], b[c][kc], acc[r][c], 0,0,0);
    __builtin_amdgcn_s_setprio(0);
    asm volatile("s_barrier" ::: "memory");

    // ---- phase 2: quad (mh0,nh1); ds: B[2..3]x2; stage B_even(t+1)
    #pragma unroll
    for (int c=0;c<2;c++)
      #pragma unroll
      for (int kc=0;kc<2;kc++)
        b[2+c][kc] = *(const bf16x8*)(sBc + oB[kc] + (2+c)*1024);
    if (pf){ async_copy16(Wb + sOffB[0][0] + kk, dB + sLdsB[0][0]);
             async_copy16(Wb + sOffB[0][1] + kk, dB + sLdsB[0][1]);
             asm volatile("s_waitcnt vmcnt(4)\n\ts_barrier" ::: "memory"); }
    else   { asm volatile("s_waitcnt vmcnt(0)\n\ts_barrier" ::: "memory"); }
    __builtin_amdgcn_sched_barrier(0);
    __builtin_amdgcn_s_setprio(1);
    #pragma unroll
    for (int r=0;r<4;r++)
      #pragma unroll
      for (int c=0;c<2;c++)
        #pragma unroll
        for (int kc=0;kc<2;kc++)
          acc[r][2+c] = __builtin_amdgcn_mfma_f32_16x16x32_bf16(a[r][kc], b[2+c][kc], acc[r][2+c], 0,0,0);
    __builtin_amdgcn_s_setprio(0);
    asm volatile("s_barrier" ::: "memory");

    // ---- phase 3: quad (mh1,nh1); ds: A[4..7]x2; stage B_odd(t+1)
    #pragma unroll
    for (int r=0;r<4;r++)
      #pragma unroll
      for (int kc=0;kc<2;kc++)
        a[r][kc] = *(const bf16x8*)(sAc + oA[kc] + 4096 + r*1024);
    if (pf){ async_copy16(Wb + sOffB[1][0] + kk, dB + sLdsB[1][0]);
             async_copy16(Wb + sOffB[1][1] + kk, dB + sLdsB[1][1]);
             asm volatile("s_waitcnt vmcnt(4)\n\ts_barrier" ::: "memory"); }
    else   { asm volatile("s_waitcnt vmcnt(0)\n\ts_barrier" ::: "memory"); }
    __builtin_amdgcn_sched_barrier(0);
    __builtin_amdgcn_s_setprio(1);
    #pragma unroll
    for (int r=0;r<4;r++)
      #pragma unroll
      for (int c=0;c<2;c++)
        #pragma unroll
        for (int kc=0;kc<2;kc++)
          acc[4+r][2+c] = __builtin_amdgcn_mfma_f32_16x16x32_bf16(a[r][kc], b[2+c][kc], acc[4+r][2+c], 0,0,0);
    __builtin_amdgcn_s_setprio(0);
    asm volatile("s_barrier" ::: "memory");

    // ---- phase 4: quad (mh1,nh0); no ds reads; stage A_hi(t+1)
    if (pf){ async_copy16(Ab + sOffA[1][0] + kk, dA + sLdsA[1][0]);
             async_copy16(Ab + sOffA[1][1] + kk, dA + sLdsA[1][1]);
             asm volatile("s_waitcnt vmcnt(4)\n\ts_barrier" ::: "memory"); }
    else   { asm volatile("s_waitcnt vmcnt(0)\n\ts_barrier" ::: "memory"); }
    __builtin_amdgcn_sched_barrier(0);
    __builtin_amdgcn_s_setprio(1);
    #pragma unroll
    for (int r=0;r<4;r++)
      #pragma unroll
      for (int c=0;c<2;c++)
        #pragma unroll
        for (int kc=0;kc<2;kc++)
          acc[4+r][c] = __builtin_amdgcn_mfma_f32_16x16x32_bf16(a[r][kc], b[c][kc], acc[4+r][c], 0,0,0);
    __builtin_amdgcn_s_setprio(0);
    asm volatile("s_barrier" ::: "memory");
  }

  if (EPI == 0){
    const int region = n0 >> 11;   // 0=Q, 1=K, 2=V (block-uniform; BN=256 divides 2048)
    const int idx0 = idxp[0];
    const int b  = m0 >> 10;
    const int s0g = m0 & 1023;
    const int hh = ((n0 & 2047) >> 7) + (wn >> 1);
    const int db = (wn & 1) * 64;
    #pragma unroll
    for (int r=0;r<8;r++){
      #pragma unroll
      for (int c=0;c<4;c++){
        const int srow = s0g + wm*128 + r*16 + lg*4;
        const int d = db + c*16 + lm;
        if (region == 0){
          #pragma unroll
          for (int g=0; g<4; g++)
            out_b[(((size_t)b*H_ + hh)*S_ + srow + g)*D_ + d] = f2b_raw(acc[r][c][g]*scale);
        } else {
          const float fp = (float)((d>>1) + 1);
          const float theta = exp2f(fp * -0.2076205059304601f);   // 10000^(-fp/64)
          const float zeta  = (fp*0.03125f + 51.2f) * (1.0f/52.2f);
          const float lz = log2f(zeta);
          const float sgn = (d & 1) ? 1.0f : -1.0f;
          #pragma unroll
          for (int g=0; g<4; g++){
            float va = acc[r][c][g];
            float part = __shfl_xor(va, 1, 64);   // partner d^1 lives in lane lm^1
            float seq = ((float)(idx0 + srow + g) - 512.0f) * (1.0f/512.0f);
            float ang = seq * theta;
            float sn, cc;
            __sincosf(ang, &sn, &cc);
            float rot = va*cc + sgn*part*sn;
            if (region == 1){
              float tt = exp2f(seq * lz);
              k_out[(((size_t)b*H_ + hh)*S_ + srow + g)*D_ + d] = f2b_raw(rot * tt);
            } else {
              // V: write into LDS transpose buffer (swizzled s8 to avoid bank conflicts)
              float ti = exp2f(-seq * lz);
              int d_local = wn*64 + c*16 + lm;
              int s_local = wm*128 + r*16 + lg*4 + g;
              int s8 = s_local >> 3;
              smem[d_local*256 + ((s8 ^ (d_local & 7))*8) + (s_local & 7)] = f2b_raw(rot * ti);
            }
          }
        }
      }
    }
    if (region == 2){
      __syncthreads();
      // coalesced store of V^T tile: 256 d-rows x 256 s, 16B units
      #pragma unroll
      for (int i=0;i<16;i++){
        int f = i*512 + tid;            // [0,8192) 16B units
        int dl = f >> 5, u = f & 31;    // u = logical s-unit
        int us = u ^ (dl & 7);
        uint4 val = *(const uint4*)(smem + dl*256 + us*8);
        int hh2 = ((n0 & 2047) >> 7) + (dl >> 7);
        *(uint4*)(vt_out + ((size_t)((size_t)b*H_ + hh2)*D_ + (dl & 127))*S_ + s0g + u*8) = val;
      }
    }
  } else {
    #pragma unroll
    for (int r=0;r<8;r++){
      #pragma unroll
      for (int c=0;c<4;c++){
        const int row0 = m0 + wm*128 + r*16 + lg*4;
        const int col  = n0 + wn*64 + c*16 + lm;
        #pragma unroll
        for (int g=0; g<4; g++){
          float vacc = acc[r][c][g];
          size_t o = (size_t)(row0 + g)*N + col;
          if (EPI == 1){
            out_f[o] = vacc + res[o];
          } else {
            out_b[o] = f2b_raw(0.5f*vacc*(1.0f + erff(vacc*0.70710678118654752f)));
          }
        }
      }
    }
  }
}

// ---------------- Flash attention (causal) ----------------
// Q,K in (B,H,S,D) bf16; V^T in (B,H,D,S) bf16; ctx out (B,S,H*D) bf16.
// grid: (qtile=16, bh=128); block 256 (4 waves x 16 q-rows). Q pre-scaled by 1/sqrt(D).
__global__ __launch_bounds__(256) void flash_attn(
    const unsigned short* __restrict__ Q, const unsigned short* __restrict__ Kx,
    const unsigned short* __restrict__ VT, unsigned short* __restrict__ ctx)
{
  __shared__ unsigned short sK[64*136];    // [k][d], stride 136 shorts
  __shared__ unsigned short sVT[128*72];   // [d][k], stride 72 shorts
  __shared__ unsigned short sP[4][16*72];  // per-wave P buffer
  const int tid = threadIdx.x, lane = tid & 63, wv = tid >> 6;
  const int lm = lane & 15, lg = lane >> 4;
  const int qt = blockIdx.x, bh = blockIdx.y;
  const size_t base = (size_t)bh * S_ * D_;
  const int qr = qt*64 + wv*16;

  bf16x8 aq[4];
  #pragma unroll
  for (int kc=0;kc<4;kc++)
    aq[kc] = *(const bf16x8*)(Q + base + (size_t)(qr + lm)*D_ + kc*32 + lg*8);

  f32x4 accO[8];
  #pragma unroll
  for (int n=0;n<8;n++) accO[n] = (f32x4){0.f,0.f,0.f,0.f};
  float mrow[4] = {-INFINITY,-INFINITY,-INFINITY,-INFINITY};
  float lrow[4] = {0.f,0.f,0.f,0.f};
  unsigned short* myP = &sP[wv][0];

  for (int kt=0; kt<=qt; ++kt){
    int k0 = kt*64;
    __syncthreads();
    #pragma unroll
    for (int i=0;i<4;i++){
      int chunk = i*256 + tid;                  // [0,1024)
      int krow = chunk >> 4, c8 = chunk & 15;   // 64 x 16
      *(uint4*)(sK + krow*136 + c8*8) = *(const uint4*)(Kx + base + (size_t)(k0+krow)*D_ + c8*8);
      int dd = chunk >> 3, c4 = chunk & 7;      // 128 x 8
      *(uint4*)(sVT + dd*72 + c4*8) = *(const uint4*)(VT + base + (size_t)dd*S_ + k0 + c4*8);
    }
    __syncthreads();
    f32x4 sc[4];
    #pragma unroll
    for (int n=0;n<4;n++){
      sc[n] = (f32x4){0.f,0.f,0.f,0.f};
      #pragma unroll
      for (int kc=0;kc<4;kc++){
        bf16x8 bk = *(const bf16x8*)(sK + (n*16+lm)*136 + kc*32 + lg*8);
        sc[n] = __builtin_amdgcn_mfma_f32_16x16x32_bf16(aq[kc], bk, sc[n], 0,0,0);
      }
    }
    if (kt == qt){
      #pragma unroll
      for (int n=0;n<4;n++)
        #pragma unroll
        for (int g=0; g<4; g++)
          if (k0 + n*16 + lm > qr + lg*4 + g) sc[n][g] = -INFINITY;
    }
    float mnew[4], alpha[4];
    #pragma unroll
    for (int g=0; g<4; g++){
      float mx = fmaxf(fmaxf(sc[0][g], sc[1][g]), fmaxf(sc[2][g], sc[3][g]));
      #pragma unroll
      for (int off=1; off<16; off<<=1) mx = fmaxf(mx, __shfl_xor(mx, off, 16));
      mnew[g] = fmaxf(mrow[g], mx);
      alpha[g] = __expf(mrow[g] - mnew[g]);
      mrow[g] = mnew[g];
    }
    #pragma unroll
    for (int n=0;n<4;n++)
      #pragma unroll
      for (int g=0; g<4; g++)
        sc[n][g] = __expf(sc[n][g] - mnew[g]);
    #pragma unroll
    for (int g=0; g<4; g++){
      float sum = sc[0][g]+sc[1][g]+sc[2][g]+sc[3][g];
      #pragma unroll
      for (int off=1; off<16; off<<=1) sum += __shfl_xor(sum, off, 16);
      lrow[g] = lrow[g]*alpha[g] + sum;
    }
    #pragma unroll
    for (int n=0;n<8;n++)
      #pragma unroll
      for (int g=0; g<4; g++) accO[n][g] *= alpha[g];
    #pragma unroll
    for (int n=0;n<4;n++)
      #pragma unroll
      for (int g=0; g<4; g++)
        myP[(lg*4+g)*72 + n*16 + lm] = f2b_raw(sc[n][g]);
    #pragma unroll
    for (int kc=0;kc<2;kc++){
      bf16x8 ap = *(const bf16x8*)(myP + lm*72 + kc*32 + lg*8);
      #pragma unroll
      for (int n=0;n<8;n++){
        bf16x8 bv = *(const bf16x8*)(sVT + (n*16+lm)*72 + kc*32 + lg*8);
        accO[n] = __builtin_amdgcn_mfma_f32_16x16x32_bf16(ap, bv, accO[n], 0,0,0);
      }
    }
  }
  const int b = bh >> 4, hh = bh & 15;
  float rl[4];
  #pragma unroll
  for (int g=0; g<4; g++) rl[g] = 1.0f / lrow[g];
  #pragma unroll
  for (int n=0;n<8;n++)
    #pragma unroll
    for (int g=0; g<4; g++){
      int srow = qr + lg*4 + g;
      int d = n*16 + lm;
      ctx[(((size_t)b*S_ + srow)*H_ + hh)*D_ + d] = f2b_raw(accO[n][g]*rl[g]);
    }
}

extern "C" void kernel_launch(void* const* d_in, const int* in_sizes, int n_in,
                              void* d_out, int out_size, void* d_ws, size_t ws_size,
                              hipStream_t stream)
{
  (void)in_sizes; (void)n_in; (void)out_size; (void)ws_size;
  const float* acts   = (const float*)d_in[0];
  const float* cachek = (const float*)d_in[1];
  const float* cachev = (const float*)d_in[2];
  const int*   idxp   = (const int*)d_in[3];
  const float* ln1w   = (const float*)d_in[4];
  const float* ln2w   = (const float*)d_in[5];
  const float* qw     = (const float*)d_in[6];
  const float* kw     = (const float*)d_in[7];
  const float* vw     = (const float*)d_in[8];
  const float* ow     = (const float*)d_in[9];
  const float* w1     = (const float*)d_in[10];
  const float* w2     = (const float*)d_in[11];
  float* out = (float*)d_out;

  // ws layout (shorts): wqkv 12.58M | wo 4.19M | w1 16.78M | w2 16.78M | xn 16.78M |
  //                     q 16.78M | k 16.78M | vt 16.78M | ctx 16.78M   (= 256 MB)
  unsigned short* wqkv = (unsigned short*)d_ws;
  unsigned short* wo_b = wqkv + 12582912;
  unsigned short* w1_b = wo_b + 4194304;
  unsigned short* w2_b = w1_b + 16777216;
  unsigned short* xn   = w2_b + 16777216;
  unsigned short* qws  = xn   + 16777216;
  unsigned short* kws  = qws  + 16777216;
  unsigned short* vtws = kws  + 16777216;
  unsigned short* ctx  = vtws + 16777216;
  unsigned short* hbuf = qws;  // 64M shorts: reuses q/k/vt/ctx (dead after O-proj)

  // 1. merged weight conversion (dst regions are contiguous from wqkv)
  cvt_all<<<49152, 256, 0, stream>>>(qw, kw, vw, ow, w1, w2, wqkv);

  // 2. LN1
  ln_kernel<<<8192, 256, 0, stream>>>(acts, ln1w, xn);

  // 3. fused QKV projection + xPos rotary + scale (one GEMM, N=6144)
  gemm_bt<0,0><<<dim3(24,32), 512, 0, stream>>>(xn, wqkv, qws, nullptr, nullptr,
                                                kws, vtws, idxp,
                                                8192, 6144, 2048, 0.08838834764831845f);

  // 4. flash attention -> ctx (B,S,HID) bf16
  flash_attn<<<dim3(16,128), 256, 0, stream>>>(qws, kws, vtws, ctx);

  // 5. O projection + residual -> d_out (f32 acts)
  gemm_bt<1,1><<<dim3(8,32), 512, 0, stream>>>(ctx, wo_b, nullptr, out, acts,
                                               nullptr, nullptr, nullptr,
                                               8192, 2048, 2048, 1.0f);

  // 6. LN2
  ln_kernel<<<8192, 256, 0, stream>>>(out, ln2w, xn);

  // 7. W1 + exact GELU -> h bf16
  gemm_bt<2,2><<<dim3(32,32), 512, 0, stream>>>(xn, w1_b, hbuf, nullptr, nullptr,
                                                nullptr, nullptr, nullptr,
                                                8192, 8192, 2048, 1.0f);

  // 8. W2 + residual (in-place on d_out)
  gemm_bt<1,3><<<dim3(8,32), 512, 0, stream>>>(hbuf, w2_b, nullptr, out, out,
                                               nullptr, nullptr, nullptr,
                                               8192, 2048, 8192, 1.0f);

  // 9. cache_k / cache_v passthrough
  hipMemcpyAsync(out + 16777216, cachek, 67108864ull, hipMemcpyDeviceToDevice, stream);
  hipMemcpyAsync(out + 33554432, cachev, 67108864ull, hipMemcpyDeviceToDevice, stream);
}